// Round 13
// baseline (849.741 us; speedup 1.0000x reference)
//
#include <hip/hip_runtime.h>

#define N_USERS 100000
#define N_ITEMS 100000
#define N_NODES (N_USERS + N_ITEMS)
#define NNZ 6400000
#define DIM 64
#define NHOPS 3
#define NODE_STRIDE ((NHOPS + 1) * DIM)   // 256 floats per node in out

#define BROWS 192                // rows per bucket
#define NBK 1042                 // ceil(200000/192)
#define NRID 8                   // staging sub-regions (≈ XCDs)
#define NSUB (NBK * NRID)        // 8336 (bucket,rid) cells
#define PTILE 8192               // edges per partition tile (2^13)
#define NTILES ((NNZ + PTILE - 1) / PTILE)   // 782
#define PGRID 512                // persistent partition blocks (2 blocks/CU)
#define P2CAP 7000               // bucket mean 6144, sigma ~78 -> +11 sigma

// ws layout (int offsets):
//   bcnt8   : [0, 8336)
//   bptr8   : [8448, 8448+8337)
//   bcur8   : [16896, 16896+8336)
//   row_ptr : [25344, 25344+200001)
//   stg     : [225536, 225536+2*NNZ)   int2; becomes row-sorted CSR in place
//   mirA    : [13025536, +NNZ)  ushort bf16
//   mirB    : [19425536, +NNZ)
// end = 25825536 ints = 103.3 MB (ws grant >= 104.8 MB proven in r4)
#define WS_BCNT8 0
#define WS_BPTR8 8448
#define WS_BCUR8 16896
#define WS_RP    25344
#define WS_STG   225536
#define WS_MIRA  13025536
#define WS_MIRB  19425536

typedef int   i32x2 __attribute__((ext_vector_type(2)));
typedef int   i32x4 __attribute__((ext_vector_type(4)));
typedef float f32x4 __attribute__((ext_vector_type(4)));

__device__ __forceinline__ unsigned short f2bf(float f) {
    unsigned u = __float_as_uint(f);
    u += 0x7fffu + ((u >> 16) & 1u);    // RNE
    return (unsigned short)(u >> 16);
}
__device__ __forceinline__ float blo(int w) {          // low bf16 of packed pair
    return __uint_as_float((unsigned)w << 16);
}
__device__ __forceinline__ float bhi(int w) {          // high bf16 of packed pair
    return __uint_as_float((unsigned)w & 0xffff0000u);
}

__global__ void zero_bcnt_kernel(int* __restrict__ bcnt8) {
    int i = blockIdx.x * blockDim.x + threadIdx.x;
    if (i < NSUB) bcnt8[i] = 0;
}

// 8-way bucket histogram: cell = (row bucket, rid = tile%8), tile = i>>13.
__global__ void bhist_kernel(const int* __restrict__ rows, int* __restrict__ bcnt8) {
    __shared__ int h[NSUB];
    for (int i = threadIdx.x; i < NSUB; i += blockDim.x) h[i] = 0;
    __syncthreads();
    int stride = gridDim.x * blockDim.x;
    for (int i = blockIdx.x * blockDim.x + threadIdx.x; i < NNZ; i += stride) {
        int rid = (i >> 13) & 7;
        atomicAdd(&h[((unsigned)rows[i] / BROWS) * NRID + rid], 1);
    }
    __syncthreads();
    for (int i = threadIdx.x; i < NSUB; i += blockDim.x)
        if (h[i]) atomicAdd(&bcnt8[i], h[i]);
}

// Exclusive scan over NSUB cells -> bptr8 (+sentinel), bcur8. One block, 1024 thr.
#define SPT 9   // ceil(8336/1024)
__global__ void bscan_kernel(const int* __restrict__ bcnt8,
                             int* __restrict__ bptr8, int* __restrict__ bcur8) {
    __shared__ int buf[1024];
    int t = threadIdx.x;
    int base = t * SPT;
    int loc[SPT];
    int s = 0;
    #pragma unroll
    for (int k = 0; k < SPT; ++k) {
        int i = base + k;
        loc[k] = (i < NSUB) ? bcnt8[i] : 0;
        s += loc[k];
    }
    buf[t] = s;
    __syncthreads();
    for (int off = 1; off < 1024; off <<= 1) {
        int v = (t >= off) ? buf[t - off] : 0;
        __syncthreads();
        buf[t] += v;
        __syncthreads();
    }
    int run = buf[t] - s;
    #pragma unroll
    for (int k = 0; k < SPT; ++k) {
        int i = base + k;
        if (i < NSUB) { bptr8[i] = run; bcur8[i] = run; }
        run += loc[k];
    }
    if (t == 0) bptr8[NSUB] = NNZ;
}

// Persistent two-phase partition; block bid handles tiles t ≡ bid (mod PGRID),
// writing ONLY into rid = bid%8 sub-regions. Non-temporal staging stores.
__global__ void __launch_bounds__(1024) partition_kernel(
        const int* __restrict__ rows, const int* __restrict__ cols,
        const float* __restrict__ vals,
        int* __restrict__ bcur8, int2* __restrict__ stg) {
    __shared__ int cur[NBK];
    const int rid = blockIdx.x & 7;
    for (int tile = blockIdx.x; tile < NTILES; tile += PGRID) {
        for (int i = threadIdx.x; i < NBK; i += 1024) cur[i] = 0;
        __syncthreads();
        const int base = tile * PTILE;
        const int end  = min(base + PTILE, NNZ);
        for (int e = base + (int)threadIdx.x; e < end; e += 1024)
            atomicAdd(&cur[(unsigned)rows[e] / BROWS], 1);
        __syncthreads();
        for (int i = threadIdx.x; i < NBK; i += 1024) {
            int c = cur[i];
            cur[i] = c ? atomicAdd(&bcur8[i * NRID + rid], c) : 0;
        }
        __syncthreads();
        for (int e = base + (int)threadIdx.x; e < end; e += 1024) {
            int r = rows[e];
            unsigned b = (unsigned)r / BROWS;
            int rl = r - (int)b * BROWS;               // 0..191
            int pos = atomicAdd(&cur[b], 1);
            i32x2 v;
            v.x = cols[e] | (rl << 18);                // col 18b | row_local 8b
            v.y = __float_as_int(vals[e]);
            __builtin_nontemporal_store(v, (i32x2*)(stg + pos));
        }
        __syncthreads();
    }
}

// Per bucket: LDS buffer, counting-sort by local row, in-place int2 CSR
// write-back (own range only), emit row_ptr.
__global__ void __launch_bounds__(256) pass2_kernel(
        const int* __restrict__ bptr8, int2* __restrict__ stg,
        int* __restrict__ row_ptr) {
    __shared__ int2 sd[P2CAP];
    __shared__ int  lh[BROWS];
    __shared__ int  lc[BROWS];
    int b = blockIdx.x;
    int s = bptr8[b * NRID];
    int e = bptr8[(b + 1) * NRID];
    int cnt = min(e - s, P2CAP);
    int t = threadIdx.x;
    for (int i = t; i < cnt; i += 256) sd[i] = stg[s + i];
    if (t < BROWS) lh[t] = 0;
    __syncthreads();
    for (int i = t; i < cnt; i += 256)
        atomicAdd(&lh[(unsigned)sd[i].x >> 18], 1);
    __syncthreads();
    int own = (t < BROWS) ? lh[t] : 0;
    for (int off = 1; off < BROWS; off <<= 1) {
        int u = (t < BROWS && t >= off) ? lh[t - off] : 0;
        __syncthreads();
        if (t < BROWS) lh[t] += u;
        __syncthreads();
    }
    int rowbase = b * BROWS;
    if (t < BROWS) {
        int ex = lh[t] - own;
        lc[t] = ex;
        if (rowbase + t < N_NODES) row_ptr[rowbase + t] = s + ex;
    }
    if (b == NBK - 1 && t == 0) row_ptr[N_NODES] = NNZ;
    __syncthreads();
    for (int i = t; i < cnt; i += 256) {
        int2 d = sd[i];
        int rl = (unsigned)d.x >> 18;
        int pos = atomicAdd(&lc[rl], 1);
        d.x &= 0x3FFFF;
        stg[s + pos] = d;
    }
}

__global__ void init_hop0_kernel(const float4* __restrict__ ue,
                                 const float4* __restrict__ ie,
                                 float* __restrict__ out,
                                 unsigned short* __restrict__ mirA) {
    int i = blockIdx.x * blockDim.x + threadIdx.x;   // node*16 + q
    if (i >= N_NODES * 16) return;
    int n = i >> 4, q = i & 15;
    float4 v = (n < N_USERS) ? ue[i] : ie[i - N_USERS * 16];
    ((float4*)(out + (size_t)n * NODE_STRIDE))[q] = v;
    ushort4 h;
    h.x = f2bf(v.x); h.y = f2bf(v.y); h.z = f2bf(v.z); h.w = f2bf(v.w);
    *(ushort4*)(mirA + ((size_t)n << 6) + q * 4) = h;
}

// bf16-gather SpMM. One wave per row; 8 lanes/edge (int4 = 16B/lane),
// 8 edges/wave x unroll 2. Non-temporal on CSR stream + out/mirror stores
// (keep L2 for the random gather lines).
__global__ void spmm_bf_kernel(const int* __restrict__ row_ptr,
                               const int2* __restrict__ csr_pair,
                               const unsigned short* __restrict__ src,
                               unsigned short* __restrict__ dst,
                               float* __restrict__ out, int hop, int write_dst) {
    int wid = (blockIdx.x * blockDim.x + threadIdx.x) >> 6;
    if (wid >= N_NODES) return;
    int lane = threadIdx.x & 63;
    int g = lane >> 3;      // edge subgroup 0..7
    int q = lane & 7;       // 8-elem chunk of DIM
    int s = row_ptr[wid];
    int e = row_ptr[wid + 1];
    float acc[8];
    #pragma unroll
    for (int k = 0; k < 8; ++k) acc[k] = 0.0f;
    int j = s + g;
    for (; j + 8 < e; j += 16) {
        i32x2 p0 = __builtin_nontemporal_load((const i32x2*)(csr_pair + j));
        i32x2 p1 = __builtin_nontemporal_load((const i32x2*)(csr_pair + j + 8));
        int4 w0 = *(const int4*)(src + ((size_t)p0.x << 6) + q * 8);
        int4 w1 = *(const int4*)(src + ((size_t)p1.x << 6) + q * 8);
        float v0 = __int_as_float(p0.y);
        float v1 = __int_as_float(p1.y);
        acc[0] += v0 * blo(w0.x); acc[1] += v0 * bhi(w0.x);
        acc[2] += v0 * blo(w0.y); acc[3] += v0 * bhi(w0.y);
        acc[4] += v0 * blo(w0.z); acc[5] += v0 * bhi(w0.z);
        acc[6] += v0 * blo(w0.w); acc[7] += v0 * bhi(w0.w);
        acc[0] += v1 * blo(w1.x); acc[1] += v1 * bhi(w1.x);
        acc[2] += v1 * blo(w1.y); acc[3] += v1 * bhi(w1.y);
        acc[4] += v1 * blo(w1.z); acc[5] += v1 * bhi(w1.z);
        acc[6] += v1 * blo(w1.w); acc[7] += v1 * bhi(w1.w);
    }
    if (j < e) {
        i32x2 p0 = __builtin_nontemporal_load((const i32x2*)(csr_pair + j));
        int4 w0 = *(const int4*)(src + ((size_t)p0.x << 6) + q * 8);
        float v0 = __int_as_float(p0.y);
        acc[0] += v0 * blo(w0.x); acc[1] += v0 * bhi(w0.x);
        acc[2] += v0 * blo(w0.y); acc[3] += v0 * bhi(w0.y);
        acc[4] += v0 * blo(w0.z); acc[5] += v0 * bhi(w0.z);
        acc[6] += v0 * blo(w0.w); acc[7] += v0 * bhi(w0.w);
    }
    #pragma unroll
    for (int k = 0; k < 8; ++k) {
        acc[k] += __shfl_xor(acc[k], 8);
        acc[k] += __shfl_xor(acc[k], 16);
        acc[k] += __shfl_xor(acc[k], 32);
    }
    if (g == 0) {
        float* op = out + (size_t)wid * NODE_STRIDE + hop * DIM + q * 8;
        f32x4 o0 = {acc[0], acc[1], acc[2], acc[3]};
        f32x4 o1 = {acc[4], acc[5], acc[6], acc[7]};
        __builtin_nontemporal_store(o0, (f32x4*)op);
        __builtin_nontemporal_store(o1, (f32x4*)(op + 4));
        if (write_dst) {
            i32x4 h;
            h.x = (int)f2bf(acc[0]) | ((int)f2bf(acc[1]) << 16);
            h.y = (int)f2bf(acc[2]) | ((int)f2bf(acc[3]) << 16);
            h.z = (int)f2bf(acc[4]) | ((int)f2bf(acc[5]) << 16);
            h.w = (int)f2bf(acc[6]) | ((int)f2bf(acc[7]) << 16);
            __builtin_nontemporal_store(h, (i32x4*)(dst + ((size_t)wid << 6) + q * 8));
        }
    }
}

extern "C" void kernel_launch(void* const* d_in, const int* in_sizes, int n_in,
                              void* d_out, int out_size, void* d_ws, size_t ws_size,
                              hipStream_t stream) {
    const float* user_e = (const float*)d_in[0];
    const float* item_e = (const float*)d_in[1];
    const float* vals   = (const float*)d_in[2];
    const int*   rows   = (const int*)d_in[3];
    const int*   cols   = (const int*)d_in[4];
    float* out = (float*)d_out;

    int*  wsi     = (int*)d_ws;
    int*  bcnt8   = wsi + WS_BCNT8;
    int*  bptr8   = wsi + WS_BPTR8;
    int*  bcur8   = wsi + WS_BCUR8;
    int*  row_ptr = wsi + WS_RP;
    int2* stg     = (int2*)(wsi + WS_STG);
    unsigned short* mirA = (unsigned short*)(wsi + WS_MIRA);
    unsigned short* mirB = (unsigned short*)(wsi + WS_MIRB);

    hipLaunchKernelGGL(zero_bcnt_kernel, dim3((NSUB + 255) / 256), dim3(256), 0, stream, bcnt8);
    hipLaunchKernelGGL(bhist_kernel, dim3(1024), dim3(256), 0, stream, rows, bcnt8);
    hipLaunchKernelGGL(bscan_kernel, dim3(1), dim3(1024), 0, stream, bcnt8, bptr8, bcur8);
    hipLaunchKernelGGL(partition_kernel, dim3(PGRID), dim3(1024), 0, stream,
                       rows, cols, vals, bcur8, stg);
    hipLaunchKernelGGL(pass2_kernel, dim3(NBK), dim3(256), 0, stream, bptr8, stg, row_ptr);
    hipLaunchKernelGGL(init_hop0_kernel, dim3((N_NODES * 16 + 255) / 256), dim3(256), 0, stream,
                       (const float4*)user_e, (const float4*)item_e, out, mirA);

    const dim3 sg((N_NODES * 64 + 255) / 256), sb(256);
    // h1: A->B,  h2: B->A,  h3: A-> (no dst)
    hipLaunchKernelGGL(spmm_bf_kernel, sg, sb, 0, stream, row_ptr, stg, mirA, mirB, out, 1, 1);
    hipLaunchKernelGGL(spmm_bf_kernel, sg, sb, 0, stream, row_ptr, stg, mirB, mirA, out, 2, 1);
    hipLaunchKernelGGL(spmm_bf_kernel, sg, sb, 0, stream, row_ptr, stg, mirA, mirB, out, 3, 0);
}

// Round 14
// 642.164 us; speedup vs baseline: 1.3232x; 1.3232x over previous
//
#include <hip/hip_runtime.h>

#define N_USERS 100000
#define N_ITEMS 100000
#define N_NODES (N_USERS + N_ITEMS)
#define NNZ 6400000
#define DIM 64
#define NHOPS 3
#define NODE_STRIDE ((NHOPS + 1) * DIM)   // 256 floats per node in out

#define BROWS 192                // rows per bucket
#define NBK 1042                 // ceil(200000/192)
#define NRID 8                   // staging sub-regions (≈ XCDs)
#define NSUB (NBK * NRID)        // 8336 (bucket,rid) cells
#define PTILE 8192               // edges per partition tile (2^13)
#define NTILES ((NNZ + PTILE - 1) / PTILE)   // 782
#define PGRID 512                // persistent partition blocks (2 blocks/CU)
#define P2CAP 7000               // bucket mean 6144, sigma ~78 -> +11 sigma

// ws layout (int offsets):
//   bcnt8   : [0, 8336)
//   bptr8   : [8448, 8448+8337)
//   bcur8   : [16896, 16896+8336)
//   row_ptr : [25344, 25344+200001)
//   stg     : [225536, 225536+2*NNZ)   int2; becomes row-sorted CSR in place
//   mirA    : [13025536, +NNZ)  ushort bf16
//   mirB    : [19425536, +NNZ)
// end = 25825536 ints = 103.3 MB (ws grant >= 104.8 MB proven in r4)
#define WS_BCNT8 0
#define WS_BPTR8 8448
#define WS_BCUR8 16896
#define WS_RP    25344
#define WS_STG   225536
#define WS_MIRA  13025536
#define WS_MIRB  19425536

__device__ __forceinline__ unsigned short f2bf(float f) {
    unsigned u = __float_as_uint(f);
    u += 0x7fffu + ((u >> 16) & 1u);    // RNE
    return (unsigned short)(u >> 16);
}
__device__ __forceinline__ float blo(int w) {          // low bf16 of packed pair
    return __uint_as_float((unsigned)w << 16);
}
__device__ __forceinline__ float bhi(int w) {          // high bf16 of packed pair
    return __uint_as_float((unsigned)w & 0xffff0000u);
}

__global__ void zero_bcnt_kernel(int* __restrict__ bcnt8) {
    int i = blockIdx.x * blockDim.x + threadIdx.x;
    if (i < NSUB) bcnt8[i] = 0;
}

// 8-way bucket histogram: cell = (row bucket, rid = tile%8), tile = i>>13.
__global__ void bhist_kernel(const int* __restrict__ rows, int* __restrict__ bcnt8) {
    __shared__ int h[NSUB];
    for (int i = threadIdx.x; i < NSUB; i += blockDim.x) h[i] = 0;
    __syncthreads();
    int stride = gridDim.x * blockDim.x;
    for (int i = blockIdx.x * blockDim.x + threadIdx.x; i < NNZ; i += stride) {
        int rid = (i >> 13) & 7;
        atomicAdd(&h[((unsigned)rows[i] / BROWS) * NRID + rid], 1);
    }
    __syncthreads();
    for (int i = threadIdx.x; i < NSUB; i += blockDim.x)
        if (h[i]) atomicAdd(&bcnt8[i], h[i]);
}

// Exclusive scan over NSUB cells -> bptr8 (+sentinel), bcur8. One block, 1024 thr.
#define SPT 9   // ceil(8336/1024)
__global__ void bscan_kernel(const int* __restrict__ bcnt8,
                             int* __restrict__ bptr8, int* __restrict__ bcur8) {
    __shared__ int buf[1024];
    int t = threadIdx.x;
    int base = t * SPT;
    int loc[SPT];
    int s = 0;
    #pragma unroll
    for (int k = 0; k < SPT; ++k) {
        int i = base + k;
        loc[k] = (i < NSUB) ? bcnt8[i] : 0;
        s += loc[k];
    }
    buf[t] = s;
    __syncthreads();
    for (int off = 1; off < 1024; off <<= 1) {
        int v = (t >= off) ? buf[t - off] : 0;
        __syncthreads();
        buf[t] += v;
        __syncthreads();
    }
    int run = buf[t] - s;
    #pragma unroll
    for (int k = 0; k < SPT; ++k) {
        int i = base + k;
        if (i < NSUB) { bptr8[i] = run; bcur8[i] = run; }
        run += loc[k];
    }
    if (t == 0) bptr8[NSUB] = NNZ;
}

// Persistent two-phase partition; block bid handles tiles t ≡ bid (mod PGRID),
// writing ONLY into rid = bid%8 sub-regions. 512 blocks -> 2 blocks/CU.
__global__ void __launch_bounds__(1024) partition_kernel(
        const int* __restrict__ rows, const int* __restrict__ cols,
        const float* __restrict__ vals,
        int* __restrict__ bcur8, int2* __restrict__ stg) {
    __shared__ int cur[NBK];
    const int rid = blockIdx.x & 7;
    for (int tile = blockIdx.x; tile < NTILES; tile += PGRID) {
        for (int i = threadIdx.x; i < NBK; i += 1024) cur[i] = 0;
        __syncthreads();
        const int base = tile * PTILE;
        const int end  = min(base + PTILE, NNZ);
        for (int e = base + (int)threadIdx.x; e < end; e += 1024)
            atomicAdd(&cur[(unsigned)rows[e] / BROWS], 1);
        __syncthreads();
        for (int i = threadIdx.x; i < NBK; i += 1024) {
            int c = cur[i];
            cur[i] = c ? atomicAdd(&bcur8[i * NRID + rid], c) : 0;
        }
        __syncthreads();
        for (int e = base + (int)threadIdx.x; e < end; e += 1024) {
            int r = rows[e];
            unsigned b = (unsigned)r / BROWS;
            int rl = r - (int)b * BROWS;               // 0..191
            int pos = atomicAdd(&cur[b], 1);
            int2 v;
            v.x = cols[e] | (rl << 18);                // col 18b | row_local 8b
            v.y = __float_as_int(vals[e]);
            stg[pos] = v;
        }
        __syncthreads();
    }
}

// Per bucket: LDS buffer, counting-sort by local row, in-place int2 CSR
// write-back (own range only), emit row_ptr.
__global__ void __launch_bounds__(256) pass2_kernel(
        const int* __restrict__ bptr8, int2* __restrict__ stg,
        int* __restrict__ row_ptr) {
    __shared__ int2 sd[P2CAP];
    __shared__ int  lh[BROWS];
    __shared__ int  lc[BROWS];
    int b = blockIdx.x;
    int s = bptr8[b * NRID];
    int e = bptr8[(b + 1) * NRID];
    int cnt = min(e - s, P2CAP);
    int t = threadIdx.x;
    for (int i = t; i < cnt; i += 256) sd[i] = stg[s + i];
    if (t < BROWS) lh[t] = 0;
    __syncthreads();
    for (int i = t; i < cnt; i += 256)
        atomicAdd(&lh[(unsigned)sd[i].x >> 18], 1);
    __syncthreads();
    int own = (t < BROWS) ? lh[t] : 0;
    for (int off = 1; off < BROWS; off <<= 1) {
        int u = (t < BROWS && t >= off) ? lh[t - off] : 0;
        __syncthreads();
        if (t < BROWS) lh[t] += u;
        __syncthreads();
    }
    int rowbase = b * BROWS;
    if (t < BROWS) {
        int ex = lh[t] - own;
        lc[t] = ex;
        if (rowbase + t < N_NODES) row_ptr[rowbase + t] = s + ex;
    }
    if (b == NBK - 1 && t == 0) row_ptr[N_NODES] = NNZ;
    __syncthreads();
    for (int i = t; i < cnt; i += 256) {
        int2 d = sd[i];
        int rl = (unsigned)d.x >> 18;
        int pos = atomicAdd(&lc[rl], 1);
        d.x &= 0x3FFFF;
        stg[s + pos] = d;
    }
}

__global__ void init_hop0_kernel(const float4* __restrict__ ue,
                                 const float4* __restrict__ ie,
                                 float* __restrict__ out,
                                 unsigned short* __restrict__ mirA) {
    int i = blockIdx.x * blockDim.x + threadIdx.x;   // node*16 + q
    if (i >= N_NODES * 16) return;
    int n = i >> 4, q = i & 15;
    float4 v = (n < N_USERS) ? ue[i] : ie[i - N_USERS * 16];
    ((float4*)(out + (size_t)n * NODE_STRIDE))[q] = v;
    ushort4 h;
    h.x = f2bf(v.x); h.y = f2bf(v.y); h.z = f2bf(v.z); h.w = f2bf(v.w);
    *(ushort4*)(mirA + ((size_t)n << 6) + q * 4) = h;
}

// bf16-gather SpMM. One wave per row; 8 lanes/edge (int4 = 16B/lane),
// 8 edges/wave in flight x unroll 2 = 16.
__global__ void spmm_bf_kernel(const int* __restrict__ row_ptr,
                               const int2* __restrict__ csr_pair,
                               const unsigned short* __restrict__ src,
                               unsigned short* __restrict__ dst,
                               float* __restrict__ out, int hop, int write_dst) {
    int wid = (blockIdx.x * blockDim.x + threadIdx.x) >> 6;
    if (wid >= N_NODES) return;
    int lane = threadIdx.x & 63;
    int g = lane >> 3;      // edge subgroup 0..7
    int q = lane & 7;       // 8-elem chunk of DIM
    int s = row_ptr[wid];
    int e = row_ptr[wid + 1];
    float acc[8];
    #pragma unroll
    for (int k = 0; k < 8; ++k) acc[k] = 0.0f;
    int j = s + g;
    for (; j + 8 < e; j += 16) {
        int2 p0 = csr_pair[j];
        int2 p1 = csr_pair[j + 8];
        int4 w0 = *(const int4*)(src + ((size_t)p0.x << 6) + q * 8);
        int4 w1 = *(const int4*)(src + ((size_t)p1.x << 6) + q * 8);
        float v0 = __int_as_float(p0.y);
        float v1 = __int_as_float(p1.y);
        acc[0] += v0 * blo(w0.x); acc[1] += v0 * bhi(w0.x);
        acc[2] += v0 * blo(w0.y); acc[3] += v0 * bhi(w0.y);
        acc[4] += v0 * blo(w0.z); acc[5] += v0 * bhi(w0.z);
        acc[6] += v0 * blo(w0.w); acc[7] += v0 * bhi(w0.w);
        acc[0] += v1 * blo(w1.x); acc[1] += v1 * bhi(w1.x);
        acc[2] += v1 * blo(w1.y); acc[3] += v1 * bhi(w1.y);
        acc[4] += v1 * blo(w1.z); acc[5] += v1 * bhi(w1.z);
        acc[6] += v1 * blo(w1.w); acc[7] += v1 * bhi(w1.w);
    }
    if (j < e) {
        int2 p0 = csr_pair[j];
        int4 w0 = *(const int4*)(src + ((size_t)p0.x << 6) + q * 8);
        float v0 = __int_as_float(p0.y);
        acc[0] += v0 * blo(w0.x); acc[1] += v0 * bhi(w0.x);
        acc[2] += v0 * blo(w0.y); acc[3] += v0 * bhi(w0.y);
        acc[4] += v0 * blo(w0.z); acc[5] += v0 * bhi(w0.z);
        acc[6] += v0 * blo(w0.w); acc[7] += v0 * bhi(w0.w);
    }
    #pragma unroll
    for (int k = 0; k < 8; ++k) {
        acc[k] += __shfl_xor(acc[k], 8);
        acc[k] += __shfl_xor(acc[k], 16);
        acc[k] += __shfl_xor(acc[k], 32);
    }
    if (g == 0) {
        float* op = out + (size_t)wid * NODE_STRIDE + hop * DIM + q * 8;
        *(float4*)op       = make_float4(acc[0], acc[1], acc[2], acc[3]);
        *(float4*)(op + 4) = make_float4(acc[4], acc[5], acc[6], acc[7]);
        if (write_dst) {
            int4 h;
            h.x = (int)f2bf(acc[0]) | ((int)f2bf(acc[1]) << 16);
            h.y = (int)f2bf(acc[2]) | ((int)f2bf(acc[3]) << 16);
            h.z = (int)f2bf(acc[4]) | ((int)f2bf(acc[5]) << 16);
            h.w = (int)f2bf(acc[6]) | ((int)f2bf(acc[7]) << 16);
            *(int4*)(dst + ((size_t)wid << 6) + q * 8) = h;
        }
    }
}

extern "C" void kernel_launch(void* const* d_in, const int* in_sizes, int n_in,
                              void* d_out, int out_size, void* d_ws, size_t ws_size,
                              hipStream_t stream) {
    const float* user_e = (const float*)d_in[0];
    const float* item_e = (const float*)d_in[1];
    const float* vals   = (const float*)d_in[2];
    const int*   rows   = (const int*)d_in[3];
    const int*   cols   = (const int*)d_in[4];
    float* out = (float*)d_out;

    int*  wsi     = (int*)d_ws;
    int*  bcnt8   = wsi + WS_BCNT8;
    int*  bptr8   = wsi + WS_BPTR8;
    int*  bcur8   = wsi + WS_BCUR8;
    int*  row_ptr = wsi + WS_RP;
    int2* stg     = (int2*)(wsi + WS_STG);
    unsigned short* mirA = (unsigned short*)(wsi + WS_MIRA);
    unsigned short* mirB = (unsigned short*)(wsi + WS_MIRB);

    hipLaunchKernelGGL(zero_bcnt_kernel, dim3((NSUB + 255) / 256), dim3(256), 0, stream, bcnt8);
    hipLaunchKernelGGL(bhist_kernel, dim3(1024), dim3(256), 0, stream, rows, bcnt8);
    hipLaunchKernelGGL(bscan_kernel, dim3(1), dim3(1024), 0, stream, bcnt8, bptr8, bcur8);
    hipLaunchKernelGGL(partition_kernel, dim3(PGRID), dim3(1024), 0, stream,
                       rows, cols, vals, bcur8, stg);
    hipLaunchKernelGGL(pass2_kernel, dim3(NBK), dim3(256), 0, stream, bptr8, stg, row_ptr);
    hipLaunchKernelGGL(init_hop0_kernel, dim3((N_NODES * 16 + 255) / 256), dim3(256), 0, stream,
                       (const float4*)user_e, (const float4*)item_e, out, mirA);

    const dim3 sg((N_NODES * 64 + 255) / 256), sb(256);
    // h1: A->B,  h2: B->A,  h3: A-> (no dst)
    hipLaunchKernelGGL(spmm_bf_kernel, sg, sb, 0, stream, row_ptr, stg, mirA, mirB, out, 1, 1);
    hipLaunchKernelGGL(spmm_bf_kernel, sg, sb, 0, stream, row_ptr, stg, mirB, mirA, out, 2, 1);
    hipLaunchKernelGGL(spmm_bf_kernel, sg, sb, 0, stream, row_ptr, stg, mirA, mirB, out, 3, 0);
}